// Round 1
// baseline (330.510 us; speedup 1.0000x reference)
//
#include <hip/hip_runtime.h>
#include <hip/hip_cooperative_groups.h>
#include <math.h>

namespace cg = cooperative_groups;

// GCN 2-layer, N=100K, E=3.2M, feat 1->16->2, log_softmax.
//
// R5 lessons (rocprof): (1) random-order 8B writes amplify ~2.8x at HBM ->
// sort tile in LDS, stream out coalesced. (2) per-edge binary search = 9
// dependent ds_reads -> once-per-block LDS run-offset table. (3) halve random
// gathers: xd = dinv*x, gd = dinv*gamma; factor dinv[dst] into epilogue.
//
// R6 (this round, theory-driven; no counters -- GPU acquisition timed out):
// traffic model says ~140MB => ~25us at HBM BW, measured 186.6us => overhead
// dominated. (a) Fuse scatter + 3 agg passes into ONE cooperative kernel
// (2 grid.sync's replace 3 launch+drain boundaries; the identical agg
// prologue [404 uncoalesced rowOff lines + 512-wide scan + table fill] runs
// 1x instead of 3x; dinv/xd/gd self-terms stay in registers across phases).
// (b) shfl-based scans: 18 barriers -> 2. (c) dc[cnt++] runtime indexing ->
// scratch (rule: runtime-indexed arrays go to local mem); fixed-trip
// #pragma unroll 16 with guard keeps it in VGPRs.

static constexpr int BLOCK_F   = 512;    // fused kernel threads (8 waves)
static constexpr int EPB       = 7936;   // edges per scatter tile (62 KB LDS)
static constexpr int ITERS     = (EPB + BLOCK_F - 1) / BLOCK_F;  // 16
static constexpr int CHUNK     = 256;    // nodes per bucket (pow2)
static constexpr int LOG_CHUNK = 8;
static constexpr int MAXNB     = 512;    // max buckets (N <= 131072)
static constexpr int MAXBLK    = 512;    // max scatter tiles (E <= 4.06M)
static constexpr int TABCAP    = 10240;  // run-table entries (bucket size bound)

// Legacy fallback path constants
static constexpr int BLOCK_S   = 512;
static constexpr int BLOCK_A   = 1024;

// ======================= shfl-based block scan (512 thr = 8 waves) =======================
// inclusive scan; 2 barriers instead of 18.
__device__ __forceinline__ unsigned int incl_scan512(unsigned int v,
                                                     unsigned int* wsum, int t) {
    unsigned int x = v;
#pragma unroll
    for (int off = 1; off < 64; off <<= 1) {
        unsigned int y = __shfl_up(x, off, 64);
        if ((t & 63) >= off) x += y;
    }
    if ((t & 63) == 63) wsum[t >> 6] = x;
    __syncthreads();
    if (t < 8) {
        unsigned int s = wsum[t];
#pragma unroll
        for (int off = 1; off < 8; off <<= 1) {
            unsigned int y = __shfl_up(s, off, 64);
            if (t >= off) s += y;
        }
        wsum[t] = s;
    }
    __syncthreads();
    return x + ((t >= 64) ? wsum[(t >> 6) - 1] : 0u);
}

__device__ __forceinline__ int run_adj_fallback(const unsigned int* cumx,
                                                const int* radj,
                                                unsigned int i, int nblk) {
    int lo = 0, hi = nblk - 1;
    while (lo < hi) {
        int mid = (lo + hi + 1) >> 1;
        if (cumx[mid] <= i) lo = mid; else hi = mid - 1;
    }
    return radj[lo];
}

// ======================= fused cooperative kernel =======================
// phase 0: scatter-sort edges into bucket-contiguous payload (all nblk blocks)
// grid.sync
// phase 1: deg -> dinv (reg), xd[]   | phase 2: s -> gamma -> gd[] | phase 3: d -> out
// (one prologue; acc reused; dinv/xd[n]/gd[n] self-terms carried in registers)

union SmemU {
    struct {
        unsigned long long pbuf[EPB];     // 63488 B
        unsigned int       hist[MAXNB];   // 2048 B
    } s;
    struct {
        unsigned int cumx[MAXBLK];        // 2048 B
        int          radj[MAXBLK];        // 2048 B
        float        acc[CHUNK];          // 1024 B
        int          table[TABCAP];       // 40960 B
    } a;
};                                        // union = 65536 B -> 2 blocks/CU

__global__ __launch_bounds__(BLOCK_F, 4) void fused_kernel(
    const int* __restrict__ src, const int* __restrict__ dst,
    const float* __restrict__ w, const float* __restrict__ x,
    const float* __restrict__ W1, const float* __restrict__ b1,
    const float* __restrict__ W2, const float* __restrict__ b2,
    unsigned int* __restrict__ rowOff, unsigned long long* __restrict__ payload,
    float* __restrict__ xd, float* __restrict__ gd, float* __restrict__ out,
    int N, int E, int nb, int nblk) {
    cg::grid_group grid = cg::this_grid();
    __shared__ SmemU sm;
    __shared__ unsigned int wsum[8];
    __shared__ unsigned int totsh;
    const int t   = threadIdx.x;
    const int blk = blockIdx.x;

    // ---------------- phase 0: scatter (blocks [0, nblk)) ----------------
    if (blk < nblk) {
        const int base = blk * EPB;
        const int nE   = min(EPB, E - base);
        sm.s.hist[t] = 0u;
        __syncthreads();

        int dc[ITERS];                     // static indexing -> stays in VGPRs
#pragma unroll
        for (int i = 0; i < ITERS; ++i) {
            const int k = t + i * BLOCK_F;
            int d = 0;
            if (k < nE) {
                d = dst[base + k];
                atomicAdd(&sm.s.hist[(unsigned int)d >> LOG_CHUNK], 1u);
            }
            dc[i] = d;
        }
        __syncthreads();

        const unsigned int val  = sm.s.hist[t];
        const unsigned int incl = incl_scan512(val, wsum, t);
        const unsigned int excl = incl - val;
        if (t < nb)  rowOff[(size_t)blk * (nb + 1) + t]  = excl;
        if (t == 0)  rowOff[(size_t)blk * (nb + 1) + nb] = (unsigned int)nE;
        sm.s.hist[t] = excl;               // -> cursor
        __syncthreads();

#pragma unroll
        for (int i = 0; i < ITERS; ++i) {
            const int k = t + i * BLOCK_F;
            if (k < nE) {
                const int d   = dc[i];
                const int bkt = (unsigned int)d >> LOG_CHUNK;
                const unsigned int slot = atomicAdd(&sm.s.hist[bkt], 1u);
                const unsigned long long p =
                    ((unsigned long long)__float_as_uint(w[base + k]) << 32) |
                    ((unsigned int)src[base + k] << LOG_CHUNK) |
                    (unsigned int)(d & (CHUNK - 1));
                sm.s.pbuf[slot] = p;       // random LDS write
            }
        }
        __syncthreads();
        for (int k = t; k < nE; k += BLOCK_F)    // coalesced global write-out
            payload[(size_t)base + k] = sm.s.pbuf[k];
    }
    grid.sync();

    // ---------------- aggregation prologue (ONCE; blocks [0, nb)) ----------------
    const int  b      = blk;
    const bool active = (blk < nb);
    const int  n      = b * CHUNK + t;
    unsigned int total = 0;
    float dv = 0.0f, xdn = 0.0f, gdn = 0.0f;

    if (active) {
        unsigned int len = 0, s0 = 0;
        if (t < nblk) {
            s0  = rowOff[(size_t)t * (nb + 1) + b];
            len = rowOff[(size_t)t * (nb + 1) + b + 1] - s0;
        }
        const unsigned int incl = incl_scan512(len, wsum, t);
        const unsigned int ex   = incl - len;
        if (t < nblk) {
            sm.a.cumx[t] = ex;
            sm.a.radj[t] = (int)s0 - (int)ex + t * EPB;
        }
        if (t == nblk - 1) totsh = incl;
        if (t < CHUNK) sm.a.acc[t] = 0.0f;
        __syncthreads();
        total = totsh;
        if (t < nblk) {                      // run-offset table (1 ds_read/edge later)
            const unsigned int beg = sm.a.cumx[t];
            const unsigned int end = (t == nblk - 1) ? total : sm.a.cumx[t + 1];
            const unsigned int lim = min(end, (unsigned int)TABCAP);
            const int a_ = sm.a.radj[t];
            for (unsigned int i = beg; i < lim; ++i) sm.a.table[i] = a_;
        }
        __syncthreads();

        // ---------------- phase 1: degree -> dinv (reg), xd ----------------
        for (unsigned int i = t; i < total; i += BLOCK_F) {
            const int adj = (i < TABCAP) ? sm.a.table[i]
                                         : run_adj_fallback(sm.a.cumx, sm.a.radj, i, nblk);
            const unsigned long long p = payload[(unsigned int)(adj + (int)i)];
            atomicAdd(&sm.a.acc[(unsigned int)p & (CHUNK - 1)],
                      __uint_as_float((unsigned int)(p >> 32)));
        }
        __syncthreads();
        if (t < CHUNK && n < N) {
            const float dsum = sm.a.acc[t] + 1.0f;          // self-loop fill 1.0
            dv  = (dsum > 0.0f) ? rsqrtf(dsum) : 0.0f;
            xdn = dv * x[n];
            xd[n] = xdn;
        }
        __syncthreads();
        if (t < CHUNK) sm.a.acc[t] = 0.0f;
    }
    grid.sync();

    // ---------------- phase 2: s -> gamma -> gd ----------------
    if (active) {
        for (unsigned int i = t; i < total; i += BLOCK_F) {
            const int adj = (i < TABCAP) ? sm.a.table[i]
                                         : run_adj_fallback(sm.a.cumx, sm.a.radj, i, nblk);
            const unsigned long long p = payload[(unsigned int)(adj + (int)i)];
            const unsigned int lo = (unsigned int)p;
            atomicAdd(&sm.a.acc[lo & (CHUNK - 1)],
                      __uint_as_float((unsigned int)(p >> 32)) *
                          xd[(int)(lo >> LOG_CHUNK)]);       // dinv[dst] factored out
        }
        __syncthreads();
        if (t < CHUNK && n < N) {
            const float sv = dv * (sm.a.acc[t] + xdn);       // + self-loop dv*dv*x[n]
            float g = 0.0f;
#pragma unroll
            for (int f = 0; f < 16; ++f) {
                const float h = fmaxf(sv * W1[f] + b1[f], 0.0f);   // relu(layer1)
                g += h * (W2[2 * f + 1] - W2[2 * f + 0]);          // gamma = g1-g0
            }
            gdn = dv * g;                                    // pre-scaled for layer 2
            gd[n] = gdn;
        }
        __syncthreads();
        if (t < CHUNK) sm.a.acc[t] = 0.0f;
    }
    grid.sync();

    // ---------------- phase 3: d -> log_softmax out ----------------
    if (active) {
        for (unsigned int i = t; i < total; i += BLOCK_F) {
            const int adj = (i < TABCAP) ? sm.a.table[i]
                                         : run_adj_fallback(sm.a.cumx, sm.a.radj, i, nblk);
            const unsigned long long p = payload[(unsigned int)(adj + (int)i)];
            const unsigned int lo = (unsigned int)p;
            atomicAdd(&sm.a.acc[lo & (CHUNK - 1)],
                      __uint_as_float((unsigned int)(p >> 32)) *
                          gd[(int)(lo >> LOG_CHUNK)]);
        }
        __syncthreads();
        if (t < CHUNK && n < N) {
            const float d = dv * (sm.a.acc[t] + gdn) + (b2[1] - b2[0]);
            // 2-class log_softmax from d = a1 - a0 (stable)
            const float lse = fmaxf(d, 0.0f) + log1pf(expf(-fabsf(d)));
            out[2 * n + 0] = -lse;
            out[2 * n + 1] = d - lse;
        }
    }
}

// ======================= fallback: previous 4-kernel tiled path =======================

__global__ __launch_bounds__(BLOCK_S) void scatter_kernel(
    const int* __restrict__ src, const int* __restrict__ dst,
    const float* __restrict__ w,
    unsigned int* __restrict__ rowOff,
    unsigned long long* __restrict__ payload,
    int E, int nb) {
    __shared__ unsigned long long pbuf[EPB];
    __shared__ unsigned int hist[MAXNB];
    __shared__ unsigned int wsum[8];
    const int blk  = blockIdx.x;
    const int base = blk * EPB;
    const int nE   = min(EPB, E - base);
    const int t    = threadIdx.x;

    hist[t] = 0u;
    __syncthreads();

    int dc[ITERS];
#pragma unroll
    for (int i = 0; i < ITERS; ++i) {
        const int k = t + i * BLOCK_S;
        int d = 0;
        if (k < nE) {
            d = dst[base + k];
            atomicAdd(&hist[(unsigned int)d >> LOG_CHUNK], 1u);
        }
        dc[i] = d;
    }
    __syncthreads();

    const unsigned int val  = hist[t];
    const unsigned int incl = incl_scan512(val, wsum, t);
    const unsigned int excl = incl - val;
    if (t < nb) rowOff[(size_t)blk * (nb + 1) + t] = excl;
    if (t == 0) rowOff[(size_t)blk * (nb + 1) + nb] = (unsigned int)nE;
    hist[t] = excl;
    __syncthreads();

#pragma unroll
    for (int i = 0; i < ITERS; ++i) {
        const int k = t + i * BLOCK_S;
        if (k < nE) {
            const int d = dc[i];
            const int bkt = (unsigned int)d >> LOG_CHUNK;
            const unsigned int slot = atomicAdd(&hist[bkt], 1u);
            const unsigned long long p =
                ((unsigned long long)__float_as_uint(w[base + k]) << 32) |
                ((unsigned int)src[base + k] << LOG_CHUNK) |
                (unsigned int)(d & (CHUNK - 1));
            pbuf[slot] = p;
        }
    }
    __syncthreads();
    for (int k = t; k < nE; k += BLOCK_S)
        payload[(size_t)base + k] = pbuf[k];
}

#define AGG_PROLOGUE                                                          \
    const int b = blockIdx.x, t = threadIdx.x;                                \
    unsigned int len = 0, s0 = 0;                                             \
    if (t < MAXBLK) {                                                         \
        if (t < nblk) {                                                       \
            s0  = rowOff[(size_t)t * (nb + 1) + b];                           \
            len = rowOff[(size_t)t * (nb + 1) + b + 1] - s0;                  \
        }                                                                     \
        sc[t] = len;                                                          \
    }                                                                         \
    __syncthreads();                                                          \
    for (int off = 1; off < MAXBLK; off <<= 1) {                              \
        unsigned int v = 0;                                                   \
        if (t < MAXBLK && t >= off) v = sc[t - off];                          \
        __syncthreads();                                                      \
        if (t < MAXBLK) sc[t] += v;                                           \
        __syncthreads();                                                      \
    }                                                                         \
    if (t < nblk) {                                                           \
        unsigned int ex = sc[t] - len;                                        \
        cumx[t] = ex;                                                         \
        radj[t] = (int)s0 - (int)ex + t * EPB;                                \
    }                                                                         \
    if (t == nblk - 1) totsh = sc[t];                                         \
    __syncthreads();                                                          \
    const unsigned int total = totsh;                                         \
    if (t < nblk) {                                                           \
        unsigned int beg = cumx[t];                                           \
        unsigned int end = (t == nblk - 1) ? total : cumx[t + 1];             \
        unsigned int lim = min(end, (unsigned int)TABCAP);                    \
        int a = radj[t];                                                      \
        for (unsigned int i = beg; i < lim; ++i) table[i] = a;                \
    }                                                                         \
    __syncthreads();

__global__ __launch_bounds__(BLOCK_A) void deg_dinv_kernel(
    const unsigned long long* __restrict__ payload,
    const unsigned int* __restrict__ rowOff,
    const float* __restrict__ x,
    float* __restrict__ dinv, float* __restrict__ xd,
    int N, int nb, int nblk) {
    __shared__ unsigned int sc[MAXBLK];
    __shared__ unsigned int cumx[MAXBLK];
    __shared__ int          radj[MAXBLK];
    __shared__ float        acc[CHUNK];
    __shared__ int          table[TABCAP];
    __shared__ unsigned int totsh;
    if (threadIdx.x < CHUNK) acc[threadIdx.x] = 0.0f;
    AGG_PROLOGUE
    for (unsigned int i = t; i < total; i += BLOCK_A) {
        int adj = (i < TABCAP) ? table[i] : run_adj_fallback(cumx, radj, i, nblk);
        unsigned long long p = payload[(unsigned int)(adj + (int)i)];
        float wv = __uint_as_float((unsigned int)(p >> 32));
        atomicAdd(&acc[(unsigned int)p & (CHUNK - 1)], wv);
    }
    __syncthreads();
    int n = b * CHUNK + t;
    if (t < CHUNK && n < N) {
        float d = acc[t] + 1.0f;
        float r = (d > 0.0f) ? rsqrtf(d) : 0.0f;
        dinv[n] = r;
        xd[n]   = r * x[n];
    }
}

__global__ __launch_bounds__(BLOCK_A) void s_gamma_kernel(
    const unsigned long long* __restrict__ payload,
    const unsigned int* __restrict__ rowOff,
    const float* __restrict__ dinv,
    const float* __restrict__ xd,
    const float* __restrict__ W1,
    const float* __restrict__ b1,
    const float* __restrict__ W2,
    float* __restrict__ gd, int N, int nb, int nblk) {
    __shared__ unsigned int sc[MAXBLK];
    __shared__ unsigned int cumx[MAXBLK];
    __shared__ int          radj[MAXBLK];
    __shared__ float        acc[CHUNK];
    __shared__ int          table[TABCAP];
    __shared__ unsigned int totsh;
    if (threadIdx.x < CHUNK) acc[threadIdx.x] = 0.0f;
    AGG_PROLOGUE
    for (unsigned int i = t; i < total; i += BLOCK_A) {
        int adj = (i < TABCAP) ? table[i] : run_adj_fallback(cumx, radj, i, nblk);
        unsigned long long p = payload[(unsigned int)(adj + (int)i)];
        float wv = __uint_as_float((unsigned int)(p >> 32));
        unsigned int lo32 = (unsigned int)p;
        int si = (int)(lo32 >> LOG_CHUNK);
        atomicAdd(&acc[lo32 & (CHUNK - 1)], wv * xd[si]);
    }
    __syncthreads();
    int n = b * CHUNK + t;
    if (t < CHUNK && n < N) {
        float dv = dinv[n];
        float sv = dv * (acc[t] + xd[n]);
        float g = 0.0f;
#pragma unroll
        for (int f = 0; f < 16; ++f) {
            float h = fmaxf(sv * W1[f] + b1[f], 0.0f);
            g += h * (W2[2 * f + 1] - W2[2 * f + 0]);
        }
        gd[n] = dv * g;
    }
}

__global__ __launch_bounds__(BLOCK_A) void d_out_kernel(
    const unsigned long long* __restrict__ payload,
    const unsigned int* __restrict__ rowOff,
    const float* __restrict__ dinv,
    const float* __restrict__ gd,
    const float* __restrict__ b2,
    float* __restrict__ out, int N, int nb, int nblk) {
    __shared__ unsigned int sc[MAXBLK];
    __shared__ unsigned int cumx[MAXBLK];
    __shared__ int          radj[MAXBLK];
    __shared__ float        acc[CHUNK];
    __shared__ int          table[TABCAP];
    __shared__ unsigned int totsh;
    if (threadIdx.x < CHUNK) acc[threadIdx.x] = 0.0f;
    AGG_PROLOGUE
    for (unsigned int i = t; i < total; i += BLOCK_A) {
        int adj = (i < TABCAP) ? table[i] : run_adj_fallback(cumx, radj, i, nblk);
        unsigned long long p = payload[(unsigned int)(adj + (int)i)];
        float wv = __uint_as_float((unsigned int)(p >> 32));
        unsigned int lo32 = (unsigned int)p;
        int si = (int)(lo32 >> LOG_CHUNK);
        atomicAdd(&acc[lo32 & (CHUNK - 1)], wv * gd[si]);
    }
    __syncthreads();
    int n = b * CHUNK + t;
    if (t < CHUNK && n < N) {
        float dv = dinv[n];
        float d = dv * (acc[t] + gd[n]) + (b2[1] - b2[0]);
        float lse = fmaxf(d, 0.0f) + log1pf(expf(-fabsf(d)));
        out[2 * n + 0] = -lse;
        out[2 * n + 1] = d - lse;
    }
}

// ======================= fallback: R3 global-atomic path =======================

static constexpr int BLOCK = 256;

__global__ void zero_kernel(float* __restrict__ a, float* __restrict__ b, int n2) {
    int i = blockIdx.x * blockDim.x + threadIdx.x;
    if (i < n2) { a[i] = 0.0f; b[i] = 0.0f; }
}
__global__ void deg_kernel(const int* __restrict__ dst, const float* __restrict__ w,
                           float* __restrict__ deg, int E) {
    int e = blockIdx.x * blockDim.x + threadIdx.x;
    if (e < E) atomicAdd(&deg[dst[e]], w[e]);
}
__global__ void dinv_kernel(float* __restrict__ deg, int N) {
    int n = blockIdx.x * blockDim.x + threadIdx.x;
    if (n < N) {
        float d = deg[n] + 1.0f;
        deg[n] = (d > 0.0f) ? rsqrtf(d) : 0.0f;
    }
}
__global__ void s_kernel(const int* __restrict__ src, const int* __restrict__ dst,
                         const float* __restrict__ w, const float* __restrict__ dinv,
                         const float* __restrict__ x, float* __restrict__ s, int E) {
    int e = blockIdx.x * blockDim.x + threadIdx.x;
    if (e < E) {
        int si = src[e], di = dst[e];
        atomicAdd(&s[di], dinv[si] * w[e] * dinv[di] * x[si]);
    }
}
__global__ void g_kernel(const float* __restrict__ s, const float* __restrict__ dinv,
                         const float* __restrict__ x, const float* __restrict__ W1,
                         const float* __restrict__ b1, const float* __restrict__ W2,
                         float2* __restrict__ g, int N) {
    int n = blockIdx.x * blockDim.x + threadIdx.x;
    if (n < N) {
        float dv = dinv[n];
        float sv = s[n] + dv * dv * x[n];
        float g0 = 0.0f, g1 = 0.0f;
#pragma unroll
        for (int f = 0; f < 16; ++f) {
            float h = fmaxf(sv * W1[f] + b1[f], 0.0f);
            g0 += h * W2[2 * f + 0];
            g1 += h * W2[2 * f + 1];
        }
        g[n] = make_float2(g0, g1);
    }
}
__global__ void agg2_kernel(const int* __restrict__ src, const int* __restrict__ dst,
                            const float* __restrict__ w, const float* __restrict__ dinv,
                            const float2* __restrict__ g, float* __restrict__ agg, int E) {
    int e = blockIdx.x * blockDim.x + threadIdx.x;
    if (e < E) {
        int si = src[e], di = dst[e];
        float norm = dinv[si] * w[e] * dinv[di];
        float2 gv = g[si];
        atomicAdd(&agg[2 * di + 0], norm * gv.x);
        atomicAdd(&agg[2 * di + 1], norm * gv.y);
    }
}
__global__ void out_kernel(float* __restrict__ out, const float* __restrict__ dinv,
                           const float2* __restrict__ g, const float* __restrict__ b2, int N) {
    int n = blockIdx.x * blockDim.x + threadIdx.x;
    if (n < N) {
        float dv2 = dinv[n] * dinv[n];
        float2 gv = g[n];
        float a0 = out[2 * n + 0] + dv2 * gv.x + b2[0];
        float a1 = out[2 * n + 1] + dv2 * gv.y + b2[1];
        float m = fmaxf(a0, a1);
        float lse = m + logf(expf(a0 - m) + expf(a1 - m));
        out[2 * n + 0] = a0 - lse;
        out[2 * n + 1] = a1 - lse;
    }
}

// ======================= launch =======================

extern "C" void kernel_launch(void* const* d_in, const int* in_sizes, int n_in,
                              void* d_out, int out_size, void* d_ws, size_t ws_size,
                              hipStream_t stream) {
    const float* x  = (const float*)d_in[0];
    const int*   ei = (const int*)d_in[1];     // [2, E] delivered as int32
    const float* w  = (const float*)d_in[2];
    const float* W1 = (const float*)d_in[3];
    const float* b1 = (const float*)d_in[4];
    const float* W2 = (const float*)d_in[5];
    const float* b2 = (const float*)d_in[6];
    float* out = (float*)d_out;

    const int N = in_sizes[0];
    const int E = in_sizes[2];
    const int* src = ei;
    const int* dst = ei + E;

    const int nb   = (N + CHUNK - 1) / CHUNK;   // 391
    const int nblk = (E + EPB - 1) / EPB;       // 404

    // ws layout: payload | rowOff | dinv | xd | gd   (dinv only used by fallback)
    size_t off = 0;
    size_t payload_off = off;  off += (size_t)nblk * EPB * 8;
    size_t rowoff_off  = off;  off += (size_t)nblk * (nb + 1) * 4;
    off = (off + 7) & ~(size_t)7;
    size_t dinv_off    = off;  off += (size_t)N * 4;
    size_t xd_off      = off;  off += (size_t)N * 4;
    size_t gd_off      = off;  off += (size_t)N * 4;
    const size_t required = off;

    // one-time cooperative-launch capability check (host queries only; no
    // enqueue -> graph-capture-safe; cached in statics)
    static int s_coop = -1;
    static int s_maxBlocks = 0;
    if (s_coop < 0) {
        int dev = 0;
        (void)hipGetDevice(&dev);
        int supp = 0;
        if (hipDeviceGetAttribute(&supp, hipDeviceAttributeCooperativeLaunch, dev)
                != hipSuccess) supp = 0;
        int nCU = 0;
        if (hipDeviceGetAttribute(&nCU, hipDeviceAttributeMultiprocessorCount, dev)
                != hipSuccess) nCU = 0;
        int perCU = 0;
        if (hipOccupancyMaxActiveBlocksPerMultiprocessor(&perCU, fused_kernel,
                BLOCK_F, 0) != hipSuccess) perCU = 0;
        s_maxBlocks = nCU * perCU;
        s_coop = supp ? 1 : 0;
    }

    const int gridF = (nblk > nb) ? nblk : nb;
    const bool fits = (nb <= MAXNB && nb <= BLOCK_F && nblk <= MAXBLK &&
                       ws_size >= required);

    if (fits && s_coop == 1 && gridF <= s_maxBlocks) {
        char* wsb = (char*)d_ws;
        unsigned long long* payload = (unsigned long long*)(wsb + payload_off);
        unsigned int* rowOff = (unsigned int*)(wsb + rowoff_off);
        float* xd = (float*)(wsb + xd_off);
        float* gd = (float*)(wsb + gd_off);

        int Nv = N, Ev = E, nbv = nb, nblkv = nblk;
        void* args[] = {(void*)&src, (void*)&dst, (void*)&w, (void*)&x,
                        (void*)&W1, (void*)&b1, (void*)&W2, (void*)&b2,
                        (void*)&rowOff, (void*)&payload,
                        (void*)&xd, (void*)&gd, (void*)&out,
                        (void*)&Nv, (void*)&Ev, (void*)&nbv, (void*)&nblkv};
        hipError_t err = hipLaunchCooperativeKernel(
            (const void*)fused_kernel, dim3(gridF), dim3(BLOCK_F), args, 0, stream);
        if (err == hipSuccess) return;
        // fall through to the proven 4-kernel path on launch failure
    }

    if (fits) {
        char* wsb = (char*)d_ws;
        unsigned long long* payload = (unsigned long long*)(wsb + payload_off);
        unsigned int* rowOff = (unsigned int*)(wsb + rowoff_off);
        float* dinv = (float*)(wsb + dinv_off);
        float* xd   = (float*)(wsb + xd_off);
        float* gd   = (float*)(wsb + gd_off);

        scatter_kernel <<<nblk, BLOCK_S, 0, stream>>>(src, dst, w, rowOff, payload, E, nb);
        deg_dinv_kernel<<<nb,   BLOCK_A, 0, stream>>>(payload, rowOff, x, dinv, xd, N, nb, nblk);
        s_gamma_kernel <<<nb,   BLOCK_A, 0, stream>>>(payload, rowOff, dinv, xd, W1, b1, W2,
                                                      gd, N, nb, nblk);
        d_out_kernel   <<<nb,   BLOCK_A, 0, stream>>>(payload, rowOff, dinv, gd, b2,
                                                      out, N, nb, nblk);
    } else {
        // R3 fallback: global-atomic path (needs 4N floats of ws)
        float*  ws   = (float*)d_ws;
        float*  dinv = ws;
        float*  s    = ws + (size_t)N;
        float2* g    = (float2*)(ws + (size_t)2 * N);
        const int gridE  = (E + BLOCK - 1) / BLOCK;
        const int gridN  = (N + BLOCK - 1) / BLOCK;
        const int gridN2 = (2 * N + BLOCK - 1) / BLOCK;
        zero_kernel<<<gridN2, BLOCK, 0, stream>>>(ws, out, 2 * N);
        deg_kernel <<<gridE,  BLOCK, 0, stream>>>(dst, w, dinv, E);
        dinv_kernel<<<gridN,  BLOCK, 0, stream>>>(dinv, N);
        s_kernel   <<<gridE,  BLOCK, 0, stream>>>(src, dst, w, dinv, x, s, E);
        g_kernel   <<<gridN,  BLOCK, 0, stream>>>(s, dinv, x, W1, b1, W2, g, N);
        agg2_kernel<<<gridE,  BLOCK, 0, stream>>>(src, dst, w, dinv, g, out, E);
        out_kernel <<<gridN,  BLOCK, 0, stream>>>(out, dinv, g, b2, N);
    }
}

// Round 2
// 318.179 us; speedup vs baseline: 1.0388x; 1.0388x over previous
//
#include <hip/hip_runtime.h>
#include <math.h>

// GCN 2-layer, N=100K, E=3.2M, feat 1->16->2, log_softmax.
//
// R5 lessons (rocprof): (1) random-order 8B writes amplify ~2.8x at HBM ->
// sort tile in LDS, stream out coalesced. (2) per-edge binary search = 9
// dependent ds_reads -> once-per-block LDS run-offset table. (3) halve random
// gathers: xd = dinv*x, gd = dinv*gamma; factor dinv[dst] into epilogue.
//
// R6 lesson (rocprof on fused coop kernel): VALUBusy 2.4%, occupancy 12
// waves/CU -> fusing into one 512-thr/66KB-LDS coop kernel destroyed TLP and
// added ~90us coop-launch overhead. Latency-bound, not launch-bound. Revert
// to 4-kernel skeleton and attack latency directly:
//  (a) deg folded into scatter (global atomics, fire-and-forget) -> one
//      fewer edge pass; deg->dinv,xd is a trivial N-thread kernel.
//  (b) agg inner loop: 4-wide MLP unroll (4 independent table/payload/gather
//      chains in flight instead of 1).
//  (c) agg blocks back to 1024 thr (~32 waves/CU), shfl scan (2 barriers).
//  (d) rowOff transposed: agg prologue reads coalesced; scatter absorbs the
//      scattered (fire-and-forget) writes.
//  (e) payload write-out vectorized to 16B.

static constexpr int BLOCK_S   = 512;    // scatter threads
static constexpr int EPB       = 7936;   // edges per scatter tile (62 KB LDS)
static constexpr int ITERS     = (EPB + BLOCK_S - 1) / BLOCK_S;  // 16
static constexpr int CHUNK     = 256;    // nodes per bucket (pow2)
static constexpr int LOG_CHUNK = 8;
static constexpr int BLOCK_A   = 1024;   // aggregation threads
static constexpr int MAXNB     = 512;    // max buckets (N <= 131072)
static constexpr int MAXBLK    = 512;    // max scatter tiles (E <= 4.06M)
static constexpr int TABCAP    = 10240;  // run-table entries (bucket size bound)

// ======================= shfl-based scans =======================
// 512-thread inclusive scan (scatter): 2 barriers.
__device__ __forceinline__ unsigned int incl_scan512(unsigned int v,
                                                     unsigned int* wsum, int t) {
    unsigned int x = v;
#pragma unroll
    for (int off = 1; off < 64; off <<= 1) {
        unsigned int y = __shfl_up(x, off, 64);
        if ((t & 63) >= off) x += y;
    }
    if ((t & 63) == 63) wsum[t >> 6] = x;
    __syncthreads();
    if (t < 8) {
        unsigned int s = wsum[t];
#pragma unroll
        for (int off = 1; off < 8; off <<= 1) {
            unsigned int y = __shfl_up(s, off, 64);
            if (t >= off) s += y;
        }
        wsum[t] = s;
    }
    __syncthreads();
    return x + ((t >= 64) ? wsum[(t >> 6) - 1] : 0u);
}

// scan of first 512 values inside a 1024-thread block (agg prologue).
__device__ __forceinline__ unsigned int incl_scan512_b1024(unsigned int v,
                                                           unsigned int* wsum, int t) {
    unsigned int x = v;
#pragma unroll
    for (int off = 1; off < 64; off <<= 1) {
        unsigned int y = __shfl_up(x, off, 64);
        if ((t & 63) >= off) x += y;
    }
    if (t < 512 && (t & 63) == 63) wsum[t >> 6] = x;
    __syncthreads();
    if (t < 8) {
        unsigned int s = wsum[t];
#pragma unroll
        for (int off = 1; off < 8; off <<= 1) {
            unsigned int y = __shfl_up(s, off, 64);
            if (t >= off) s += y;
        }
        wsum[t] = s;
    }
    __syncthreads();
    return x + ((t >= 64 && t < 512) ? wsum[(t >> 6) - 1] : 0u);
}

__device__ __forceinline__ int run_adj_fallback(const unsigned int* cumx,
                                                const int* radj,
                                                unsigned int i, int nblk) {
    int lo = 0, hi = nblk - 1;
    while (lo < hi) {
        int mid = (lo + hi + 1) >> 1;
        if (cumx[mid] <= i) lo = mid; else hi = mid - 1;
    }
    return radj[lo];
}

// ======================= scatter: LDS sort + coalesced write-out + deg =======================

__global__ __launch_bounds__(BLOCK_S) void scatter_kernel(
    const int* __restrict__ src, const int* __restrict__ dst,
    const float* __restrict__ w,
    unsigned int* __restrict__ rowOffT,        // [(nb+1)][nblk] transposed
    unsigned long long* __restrict__ payload,  // [nblk*EPB]
    float* __restrict__ deg,                   // [N], pre-zeroed
    int E, int nb, int nblk) {
    __shared__ unsigned long long pbuf[EPB];   // 63488 B staging
    __shared__ unsigned int hist[MAXNB];       // 2048 B (reused as cursor)
    __shared__ unsigned int wsum[8];
    const int blk  = blockIdx.x;
    const int base = blk * EPB;
    const int nE   = min(EPB, E - base);
    const int t    = threadIdx.x;

    hist[t] = 0u;
    __syncthreads();

    int dc[ITERS];                              // static indexing -> VGPRs
#pragma unroll
    for (int i = 0; i < ITERS; ++i) {
        const int k = t + i * BLOCK_S;
        int d = 0;
        if (k < nE) {
            d = dst[base + k];
            atomicAdd(&hist[(unsigned int)d >> LOG_CHUNK], 1u);
        }
        dc[i] = d;
    }
    __syncthreads();

    const unsigned int val  = hist[t];
    const unsigned int incl = incl_scan512(val, wsum, t);
    const unsigned int excl = incl - val;
    if (t < nb)  rowOffT[(size_t)t * nblk + blk]  = excl;   // transposed (scattered write)
    if (t == 0)  rowOffT[(size_t)nb * nblk + blk] = (unsigned int)nE;
    hist[t] = excl;                             // -> cursor
    __syncthreads();

#pragma unroll
    for (int i = 0; i < ITERS; ++i) {
        const int k = t + i * BLOCK_S;
        if (k < nE) {
            const int d   = dc[i];
            const float wv = w[base + k];
            atomicAdd(&deg[d], wv);             // fire-and-forget, L2-resident
            const int bkt = (unsigned int)d >> LOG_CHUNK;
            const unsigned int slot = atomicAdd(&hist[bkt], 1u);
            const unsigned long long p =
                ((unsigned long long)__float_as_uint(wv) << 32) |
                ((unsigned int)src[base + k] << LOG_CHUNK) |
                (unsigned int)(d & (CHUNK - 1));
            pbuf[slot] = p;                     // random LDS write
        }
    }
    __syncthreads();
    // coalesced, in-order global write-out, 16B per lane
    const int nE2 = nE & ~1;
    for (int k = 2 * t; k < nE2; k += 2 * BLOCK_S) {
        ulonglong2 v = *reinterpret_cast<const ulonglong2*>(&pbuf[k]);
        *reinterpret_cast<ulonglong2*>(&payload[(size_t)base + k]) = v;
    }
    if ((nE & 1) && t == 0) payload[(size_t)base + nE - 1] = pbuf[nE - 1];
}

// ======================= tiny per-node kernel: deg -> dinv, xd =======================

__global__ void dinv_xd_kernel(const float* __restrict__ deg,
                               const float* __restrict__ x,
                               float* __restrict__ dinv, float* __restrict__ xd,
                               int N) {
    int n = blockIdx.x * blockDim.x + threadIdx.x;
    if (n < N) {
        float d = deg[n] + 1.0f;                // self-loop fill 1.0
        float r = (d > 0.0f) ? rsqrtf(d) : 0.0f;
        dinv[n] = r;
        xd[n]   = r * x[n];
    }
}

// ======================= aggregation kernels =======================
// Prologue: coalesced transposed rowOffT reads + shfl scan (2 barriers) +
// run-offset table. Inner loop: 4-wide MLP unroll over the
// table->payload->gather->atomic chain.

#define AGG_PROLOGUE                                                          \
    const int b = blockIdx.x, t = threadIdx.x;                                \
    unsigned int len = 0, s0 = 0;                                             \
    if (t < nblk) {                                                           \
        s0  = rowOffT[(size_t)b * nblk + t];                                  \
        len = rowOffT[(size_t)(b + 1) * nblk + t] - s0;                       \
    }                                                                         \
    const unsigned int incl_ = incl_scan512_b1024(len, wsum, t);              \
    const unsigned int ex_   = incl_ - len;                                   \
    if (t < nblk) {                                                           \
        cumx[t] = ex_;                                                        \
        radj[t] = (int)s0 - (int)ex_ + t * EPB;                               \
    }                                                                         \
    if (t == nblk - 1) totsh = incl_;                                         \
    if (t < CHUNK) acc[t] = 0.0f;                                             \
    __syncthreads();                                                          \
    const unsigned int total = totsh;                                         \
    if (t < nblk) {                                                           \
        unsigned int beg = cumx[t];                                           \
        unsigned int end = (t == nblk - 1) ? total : cumx[t + 1];             \
        unsigned int lim = min(end, (unsigned int)TABCAP);                    \
        int a_ = radj[t];                                                     \
        for (unsigned int i = beg; i < lim; ++i) table[i] = a_;               \
    }                                                                         \
    __syncthreads();

#define TAB(i) (((i) < (unsigned int)TABCAP) ? table[i]                       \
                                             : run_adj_fallback(cumx, radj, (i), nblk))

__global__ __launch_bounds__(BLOCK_A) void s_gamma_kernel(
    const unsigned long long* __restrict__ payload,
    const unsigned int* __restrict__ rowOffT,
    const float* __restrict__ dinv,
    const float* __restrict__ xd,
    const float* __restrict__ W1,    // [16]
    const float* __restrict__ b1,    // [16]
    const float* __restrict__ W2,    // [16][2]
    float* __restrict__ gd, int N, int nb, int nblk) {
    __shared__ unsigned int cumx[MAXBLK];
    __shared__ int          radj[MAXBLK];
    __shared__ float        acc[CHUNK];
    __shared__ int          table[TABCAP];
    __shared__ unsigned int wsum[8];
    __shared__ unsigned int totsh;
    AGG_PROLOGUE
    unsigned int i = t;
    for (; i + 3u * BLOCK_A < total; i += 4u * BLOCK_A) {
        const unsigned int i0 = i, i1 = i + BLOCK_A, i2 = i + 2u * BLOCK_A,
                           i3 = i + 3u * BLOCK_A;
        const int a0 = TAB(i0), a1 = TAB(i1), a2 = TAB(i2), a3 = TAB(i3);
        const unsigned long long p0 = payload[(unsigned int)(a0 + (int)i0)];
        const unsigned long long p1 = payload[(unsigned int)(a1 + (int)i1)];
        const unsigned long long p2 = payload[(unsigned int)(a2 + (int)i2)];
        const unsigned long long p3 = payload[(unsigned int)(a3 + (int)i3)];
        const float f0 = xd[(int)(((unsigned int)p0) >> LOG_CHUNK)];
        const float f1 = xd[(int)(((unsigned int)p1) >> LOG_CHUNK)];
        const float f2 = xd[(int)(((unsigned int)p2) >> LOG_CHUNK)];
        const float f3 = xd[(int)(((unsigned int)p3) >> LOG_CHUNK)];
        atomicAdd(&acc[(unsigned int)p0 & (CHUNK - 1)],
                  __uint_as_float((unsigned int)(p0 >> 32)) * f0);
        atomicAdd(&acc[(unsigned int)p1 & (CHUNK - 1)],
                  __uint_as_float((unsigned int)(p1 >> 32)) * f1);
        atomicAdd(&acc[(unsigned int)p2 & (CHUNK - 1)],
                  __uint_as_float((unsigned int)(p2 >> 32)) * f2);
        atomicAdd(&acc[(unsigned int)p3 & (CHUNK - 1)],
                  __uint_as_float((unsigned int)(p3 >> 32)) * f3);
    }
    for (; i < total; i += BLOCK_A) {
        const int adj = TAB(i);
        const unsigned long long p = payload[(unsigned int)(adj + (int)i)];
        atomicAdd(&acc[(unsigned int)p & (CHUNK - 1)],
                  __uint_as_float((unsigned int)(p >> 32)) *
                      xd[(int)(((unsigned int)p) >> LOG_CHUNK)]);
    }
    __syncthreads();
    const int n = b * CHUNK + t;
    if (t < CHUNK && n < N) {
        const float dv = dinv[n];
        const float sv = dv * (acc[t] + xd[n]);   // + self-loop dv*dv*x[n]
        float g = 0.0f;
#pragma unroll
        for (int f = 0; f < 16; ++f) {
            const float h = fmaxf(sv * W1[f] + b1[f], 0.0f);   // relu(layer1)
            g += h * (W2[2 * f + 1] - W2[2 * f + 0]);          // gamma = g1-g0
        }
        gd[n] = dv * g;                           // pre-scaled for layer 2
    }
}

__global__ __launch_bounds__(BLOCK_A) void d_out_kernel(
    const unsigned long long* __restrict__ payload,
    const unsigned int* __restrict__ rowOffT,
    const float* __restrict__ dinv,
    const float* __restrict__ gd,
    const float* __restrict__ b2,    // [2]
    float* __restrict__ out, int N, int nb, int nblk) {
    __shared__ unsigned int cumx[MAXBLK];
    __shared__ int          radj[MAXBLK];
    __shared__ float        acc[CHUNK];
    __shared__ int          table[TABCAP];
    __shared__ unsigned int wsum[8];
    __shared__ unsigned int totsh;
    AGG_PROLOGUE
    unsigned int i = t;
    for (; i + 3u * BLOCK_A < total; i += 4u * BLOCK_A) {
        const unsigned int i0 = i, i1 = i + BLOCK_A, i2 = i + 2u * BLOCK_A,
                           i3 = i + 3u * BLOCK_A;
        const int a0 = TAB(i0), a1 = TAB(i1), a2 = TAB(i2), a3 = TAB(i3);
        const unsigned long long p0 = payload[(unsigned int)(a0 + (int)i0)];
        const unsigned long long p1 = payload[(unsigned int)(a1 + (int)i1)];
        const unsigned long long p2 = payload[(unsigned int)(a2 + (int)i2)];
        const unsigned long long p3 = payload[(unsigned int)(a3 + (int)i3)];
        const float f0 = gd[(int)(((unsigned int)p0) >> LOG_CHUNK)];
        const float f1 = gd[(int)(((unsigned int)p1) >> LOG_CHUNK)];
        const float f2 = gd[(int)(((unsigned int)p2) >> LOG_CHUNK)];
        const float f3 = gd[(int)(((unsigned int)p3) >> LOG_CHUNK)];
        atomicAdd(&acc[(unsigned int)p0 & (CHUNK - 1)],
                  __uint_as_float((unsigned int)(p0 >> 32)) * f0);
        atomicAdd(&acc[(unsigned int)p1 & (CHUNK - 1)],
                  __uint_as_float((unsigned int)(p1 >> 32)) * f1);
        atomicAdd(&acc[(unsigned int)p2 & (CHUNK - 1)],
                  __uint_as_float((unsigned int)(p2 >> 32)) * f2);
        atomicAdd(&acc[(unsigned int)p3 & (CHUNK - 1)],
                  __uint_as_float((unsigned int)(p3 >> 32)) * f3);
    }
    for (; i < total; i += BLOCK_A) {
        const int adj = TAB(i);
        const unsigned long long p = payload[(unsigned int)(adj + (int)i)];
        atomicAdd(&acc[(unsigned int)p & (CHUNK - 1)],
                  __uint_as_float((unsigned int)(p >> 32)) *
                      gd[(int)(((unsigned int)p) >> LOG_CHUNK)]);
    }
    __syncthreads();
    const int n = b * CHUNK + t;
    if (t < CHUNK && n < N) {
        const float dv = dinv[n];
        const float d = dv * (acc[t] + gd[n]) + (b2[1] - b2[0]);
        // 2-class log_softmax from d = a1 - a0 (stable)
        const float lse = fmaxf(d, 0.0f) + log1pf(expf(-fabsf(d)));
        out[2 * n + 0] = -lse;
        out[2 * n + 1] = d - lse;
    }
}

// ======================= fallback: R3 global-atomic path =======================

static constexpr int BLOCK = 256;

__global__ void zero_kernel(float* __restrict__ a, float* __restrict__ b, int n2) {
    int i = blockIdx.x * blockDim.x + threadIdx.x;
    if (i < n2) { a[i] = 0.0f; b[i] = 0.0f; }
}
__global__ void deg_kernel(const int* __restrict__ dst, const float* __restrict__ w,
                           float* __restrict__ deg, int E) {
    int e = blockIdx.x * blockDim.x + threadIdx.x;
    if (e < E) atomicAdd(&deg[dst[e]], w[e]);
}
__global__ void dinv_kernel(float* __restrict__ deg, int N) {
    int n = blockIdx.x * blockDim.x + threadIdx.x;
    if (n < N) {
        float d = deg[n] + 1.0f;
        deg[n] = (d > 0.0f) ? rsqrtf(d) : 0.0f;
    }
}
__global__ void s_kernel(const int* __restrict__ src, const int* __restrict__ dst,
                         const float* __restrict__ w, const float* __restrict__ dinv,
                         const float* __restrict__ x, float* __restrict__ s, int E) {
    int e = blockIdx.x * blockDim.x + threadIdx.x;
    if (e < E) {
        int si = src[e], di = dst[e];
        atomicAdd(&s[di], dinv[si] * w[e] * dinv[di] * x[si]);
    }
}
__global__ void g_kernel(const float* __restrict__ s, const float* __restrict__ dinv,
                         const float* __restrict__ x, const float* __restrict__ W1,
                         const float* __restrict__ b1, const float* __restrict__ W2,
                         float2* __restrict__ g, int N) {
    int n = blockIdx.x * blockDim.x + threadIdx.x;
    if (n < N) {
        float dv = dinv[n];
        float sv = s[n] + dv * dv * x[n];
        float g0 = 0.0f, g1 = 0.0f;
#pragma unroll
        for (int f = 0; f < 16; ++f) {
            float h = fmaxf(sv * W1[f] + b1[f], 0.0f);
            g0 += h * W2[2 * f + 0];
            g1 += h * W2[2 * f + 1];
        }
        g[n] = make_float2(g0, g1);
    }
}
__global__ void agg2_kernel(const int* __restrict__ src, const int* __restrict__ dst,
                            const float* __restrict__ w, const float* __restrict__ dinv,
                            const float2* __restrict__ g, float* __restrict__ agg, int E) {
    int e = blockIdx.x * blockDim.x + threadIdx.x;
    if (e < E) {
        int si = src[e], di = dst[e];
        float norm = dinv[si] * w[e] * dinv[di];
        float2 gv = g[si];
        atomicAdd(&agg[2 * di + 0], norm * gv.x);
        atomicAdd(&agg[2 * di + 1], norm * gv.y);
    }
}
__global__ void out_kernel(float* __restrict__ out, const float* __restrict__ dinv,
                           const float2* __restrict__ g, const float* __restrict__ b2, int N) {
    int n = blockIdx.x * blockDim.x + threadIdx.x;
    if (n < N) {
        float dv2 = dinv[n] * dinv[n];
        float2 gv = g[n];
        float a0 = out[2 * n + 0] + dv2 * gv.x + b2[0];
        float a1 = out[2 * n + 1] + dv2 * gv.y + b2[1];
        float m = fmaxf(a0, a1);
        float lse = m + logf(expf(a0 - m) + expf(a1 - m));
        out[2 * n + 0] = a0 - lse;
        out[2 * n + 1] = a1 - lse;
    }
}

// ======================= launch =======================

extern "C" void kernel_launch(void* const* d_in, const int* in_sizes, int n_in,
                              void* d_out, int out_size, void* d_ws, size_t ws_size,
                              hipStream_t stream) {
    const float* x  = (const float*)d_in[0];
    const int*   ei = (const int*)d_in[1];     // [2, E] delivered as int32
    const float* w  = (const float*)d_in[2];
    const float* W1 = (const float*)d_in[3];
    const float* b1 = (const float*)d_in[4];
    const float* W2 = (const float*)d_in[5];
    const float* b2 = (const float*)d_in[6];
    float* out = (float*)d_out;

    const int N = in_sizes[0];
    const int E = in_sizes[2];
    const int* src = ei;
    const int* dst = ei + E;

    const int nb   = (N + CHUNK - 1) / CHUNK;   // 391
    const int nblk = (E + EPB - 1) / EPB;       // 404

    // ws layout: payload | rowOffT | deg | dinv | xd | gd
    size_t off = 0;
    size_t payload_off = off;  off += (size_t)nblk * EPB * 8;
    size_t rowoff_off  = off;  off += (size_t)(nb + 1) * nblk * 4;
    off = (off + 7) & ~(size_t)7;
    size_t deg_off     = off;  off += (size_t)N * 4;
    size_t dinv_off    = off;  off += (size_t)N * 4;
    size_t xd_off      = off;  off += (size_t)N * 4;
    size_t gd_off      = off;  off += (size_t)N * 4;
    const size_t required = off;

    const bool fits = (nb <= MAXNB && nb <= BLOCK_S && nblk <= MAXBLK &&
                       ws_size >= required);

    if (fits) {
        char* wsb = (char*)d_ws;
        unsigned long long* payload = (unsigned long long*)(wsb + payload_off);
        unsigned int* rowOffT = (unsigned int*)(wsb + rowoff_off);
        float* deg  = (float*)(wsb + deg_off);
        float* dinv = (float*)(wsb + dinv_off);
        float* xd   = (float*)(wsb + xd_off);
        float* gd   = (float*)(wsb + gd_off);

        hipMemsetAsync(deg, 0, (size_t)N * 4, stream);
        scatter_kernel <<<nblk, BLOCK_S, 0, stream>>>(src, dst, w, rowOffT, payload,
                                                      deg, E, nb, nblk);
        dinv_xd_kernel <<<(N + 1023) / 1024, 1024, 0, stream>>>(deg, x, dinv, xd, N);
        s_gamma_kernel <<<nb, BLOCK_A, 0, stream>>>(payload, rowOffT, dinv, xd,
                                                    W1, b1, W2, gd, N, nb, nblk);
        d_out_kernel   <<<nb, BLOCK_A, 0, stream>>>(payload, rowOffT, dinv, gd, b2,
                                                    out, N, nb, nblk);
    } else {
        // R3 fallback: global-atomic path (needs 4N floats of ws)
        float*  ws   = (float*)d_ws;
        float*  dinv = ws;
        float*  s    = ws + (size_t)N;
        float2* g    = (float2*)(ws + (size_t)2 * N);
        const int gridE  = (E + BLOCK - 1) / BLOCK;
        const int gridN  = (N + BLOCK - 1) / BLOCK;
        const int gridN2 = (2 * N + BLOCK - 1) / BLOCK;
        zero_kernel<<<gridN2, BLOCK, 0, stream>>>(ws, out, 2 * N);
        deg_kernel <<<gridE,  BLOCK, 0, stream>>>(dst, w, dinv, E);
        dinv_kernel<<<gridN,  BLOCK, 0, stream>>>(dinv, N);
        s_kernel   <<<gridE,  BLOCK, 0, stream>>>(src, dst, w, dinv, x, s, E);
        g_kernel   <<<gridN,  BLOCK, 0, stream>>>(s, dinv, x, W1, b1, W2, g, N);
        agg2_kernel<<<gridE,  BLOCK, 0, stream>>>(src, dst, w, dinv, g, out, E);
        out_kernel <<<gridN,  BLOCK, 0, stream>>>(out, dinv, g, b2, N);
    }
}

// Round 3
// 186.395 us; speedup vs baseline: 1.7732x; 1.7070x over previous
//
#include <hip/hip_runtime.h>
#include <math.h>

// GCN 2-layer, N=100K, E=3.2M, feat 1->16->2, log_softmax.
//
// R5 lessons (rocprof): (1) random-order 8B writes amplify ~2.8x at HBM ->
// sort tile in LDS, stream out coalesced. (2) per-edge binary search = 9
// dependent ds_reads -> once-per-block LDS run-offset table. (3) halve random
// gathers: xd = dinv*x, gd = dinv*gamma; factor dinv[dst] into epilogue.
//
// R6 lesson: 66KB-LDS coop monolith -> 12 waves/CU, VALUBusy 2.4%, +90us coop
// overhead. Latency-bound => occupancy is king.
//
// R7 lesson (rocprof): folding deg into scatter via global atomicAdd cost
// ~103MB of HBM RMW traffic (WRITE_SIZE 27->130MB) and +115us: device-scope
// atomics on random addresses execute memory-side, one dirty sector per
// atomic. NEVER random global atomics on this chip. Revert: deg is an agg
// pass again (LDS atomics only).
//
// R8 (this round): scatter occupancy was capped at 39% (66KB LDS = 2
// blocks/CU, 404 blocks on 256 CUs). EPB 7936->4096: 34KB LDS -> 4
// blocks/CU, 782 resident blocks, 76% cap. Edge loads vectorized to
// int4/float4. Agg prologue scan widened to 1024 (MAXBLK 1024) with a
// 2-barrier shfl scan; aggs keep the 4-wide MLP unroll.

static constexpr int BLOCK_S   = 512;    // scatter threads
static constexpr int EPB       = 4096;   // edges per scatter tile (32 KB LDS)
static constexpr int VITERS    = EPB / (BLOCK_S * 4);  // 2 (int4 groups)
static constexpr int CHUNK     = 256;    // nodes per bucket (pow2)
static constexpr int LOG_CHUNK = 8;
static constexpr int BLOCK_A   = 1024;   // aggregation threads
static constexpr int MAXNB     = 512;    // max buckets (N <= 131072)
static constexpr int MAXBLK    = 1024;   // max scatter tiles (E <= 4.19M)
static constexpr int TABCAP    = 10240;  // run-table entries (bucket size bound)

// ======================= shfl-based scans =======================
// 512-thread inclusive scan (scatter hist): 2 barriers.
__device__ __forceinline__ unsigned int incl_scan512(unsigned int v,
                                                     unsigned int* wsum, int t) {
    unsigned int x = v;
#pragma unroll
    for (int off = 1; off < 64; off <<= 1) {
        unsigned int y = __shfl_up(x, off, 64);
        if ((t & 63) >= off) x += y;
    }
    if ((t & 63) == 63) wsum[t >> 6] = x;
    __syncthreads();
    if (t < 8) {
        unsigned int s = wsum[t];
#pragma unroll
        for (int off = 1; off < 8; off <<= 1) {
            unsigned int y = __shfl_up(s, off, 64);
            if (t >= off) s += y;
        }
        wsum[t] = s;
    }
    __syncthreads();
    return x + ((t >= 64) ? wsum[(t >> 6) - 1] : 0u);
}

// 1024-thread inclusive scan (agg prologue): 2 barriers.
__device__ __forceinline__ unsigned int incl_scan1024(unsigned int v,
                                                      unsigned int* wsum, int t) {
    unsigned int x = v;
#pragma unroll
    for (int off = 1; off < 64; off <<= 1) {
        unsigned int y = __shfl_up(x, off, 64);
        if ((t & 63) >= off) x += y;
    }
    if ((t & 63) == 63) wsum[t >> 6] = x;   // 16 wave sums
    __syncthreads();
    if (t < 16) {
        unsigned int s = wsum[t];
#pragma unroll
        for (int off = 1; off < 16; off <<= 1) {
            unsigned int y = __shfl_up(s, off, 64);
            if (t >= off) s += y;
        }
        wsum[t] = s;
    }
    __syncthreads();
    return x + ((t >= 64) ? wsum[(t >> 6) - 1] : 0u);
}

__device__ __forceinline__ int run_adj_fallback(const unsigned int* cumx,
                                                const int* radj,
                                                unsigned int i, int nblk) {
    int lo = 0, hi = nblk - 1;
    while (lo < hi) {
        int mid = (lo + hi + 1) >> 1;
        if (cumx[mid] <= i) lo = mid; else hi = mid - 1;
    }
    return radj[lo];
}

// ======================= scatter: LDS sort + coalesced write-out =======================

__global__ __launch_bounds__(BLOCK_S) void scatter_kernel(
    const int* __restrict__ src, const int* __restrict__ dst,
    const float* __restrict__ w,
    unsigned int* __restrict__ rowOffT,        // [(nb+1)][nblk] transposed
    unsigned long long* __restrict__ payload,  // [nblk*EPB]
    int E, int nb, int nblk) {
    __shared__ unsigned long long pbuf[EPB];   // 32768 B staging
    __shared__ unsigned int hist[MAXNB];       // 2048 B (reused as cursor)
    __shared__ unsigned int wsum[8];
    const int blk  = blockIdx.x;
    const int base = blk * EPB;
    const int nE   = min(EPB, E - base);       // multiple of 4 (E, EPB mult 4)
    const int t    = threadIdx.x;

    hist[t] = 0u;
    __syncthreads();

    int4 dc[VITERS];                           // static indexing -> VGPRs
#pragma unroll
    for (int i = 0; i < VITERS; ++i) {
        const int k = 4 * t + i * 4 * BLOCK_S;
        int4 d4 = make_int4(0, 0, 0, 0);
        if (k < nE) {
            d4 = *reinterpret_cast<const int4*>(&dst[base + k]);
            atomicAdd(&hist[(unsigned int)d4.x >> LOG_CHUNK], 1u);
            atomicAdd(&hist[(unsigned int)d4.y >> LOG_CHUNK], 1u);
            atomicAdd(&hist[(unsigned int)d4.z >> LOG_CHUNK], 1u);
            atomicAdd(&hist[(unsigned int)d4.w >> LOG_CHUNK], 1u);
        }
        dc[i] = d4;
    }
    __syncthreads();

    const unsigned int val  = hist[t];
    const unsigned int incl = incl_scan512(val, wsum, t);
    const unsigned int excl = incl - val;
    if (t < nb)  rowOffT[(size_t)t * nblk + blk]  = excl;   // transposed write
    if (t == 0)  rowOffT[(size_t)nb * nblk + blk] = (unsigned int)nE;
    hist[t] = excl;                             // -> cursor
    __syncthreads();

#pragma unroll
    for (int i = 0; i < VITERS; ++i) {
        const int k = 4 * t + i * 4 * BLOCK_S;
        if (k < nE) {
            const int4   d4 = dc[i];
            const int4   s4 = *reinterpret_cast<const int4*>(&src[base + k]);
            const float4 w4 = *reinterpret_cast<const float4*>(&w[base + k]);
#define SCAT_ONE(dd, ss, ww)                                                  \
            {                                                                 \
                const unsigned int slot =                                     \
                    atomicAdd(&hist[(unsigned int)(dd) >> LOG_CHUNK], 1u);    \
                pbuf[slot] =                                                  \
                    ((unsigned long long)__float_as_uint(ww) << 32) |         \
                    ((unsigned int)(ss) << LOG_CHUNK) |                       \
                    (unsigned int)((dd) & (CHUNK - 1));                       \
            }
            SCAT_ONE(d4.x, s4.x, w4.x)
            SCAT_ONE(d4.y, s4.y, w4.y)
            SCAT_ONE(d4.z, s4.z, w4.z)
            SCAT_ONE(d4.w, s4.w, w4.w)
#undef SCAT_ONE
        }
    }
    __syncthreads();
    // coalesced, in-order global write-out, 16B per lane (nE multiple of 4)
    for (int k2 = t; k2 < (nE >> 1); k2 += BLOCK_S) {
        ulonglong2 v = *reinterpret_cast<const ulonglong2*>(&pbuf[2 * k2]);
        *reinterpret_cast<ulonglong2*>(&payload[(size_t)base + 2 * k2]) = v;
    }
}

// ======================= aggregation kernels =======================
// Prologue: coalesced transposed rowOffT reads + 1024-wide shfl scan (2
// barriers) + run-offset table. Inner loop: 4-wide MLP unroll over the
// table->payload->gather->LDS-atomic chain.

#define AGG_PROLOGUE                                                          \
    const int b = blockIdx.x, t = threadIdx.x;                                \
    unsigned int len = 0, s0 = 0;                                             \
    if (t < nblk) {                                                           \
        s0  = rowOffT[(size_t)b * nblk + t];                                  \
        len = rowOffT[(size_t)(b + 1) * nblk + t] - s0;                       \
    }                                                                         \
    const unsigned int incl_ = incl_scan1024(len, wsum, t);                   \
    const unsigned int ex_   = incl_ - len;                                   \
    if (t < nblk) {                                                           \
        cumx[t] = ex_;                                                        \
        radj[t] = (int)s0 - (int)ex_ + t * EPB;                               \
    }                                                                         \
    if (t == nblk - 1) totsh = incl_;                                         \
    if (t < CHUNK) acc[t] = 0.0f;                                             \
    __syncthreads();                                                          \
    const unsigned int total = totsh;                                         \
    if (t < nblk) {                                                           \
        unsigned int beg = cumx[t];                                           \
        unsigned int end = (t == nblk - 1) ? total : cumx[t + 1];             \
        unsigned int lim = min(end, (unsigned int)TABCAP);                    \
        int a_ = radj[t];                                                     \
        for (unsigned int i = beg; i < lim; ++i) table[i] = a_;               \
    }                                                                         \
    __syncthreads();

#define TAB(i) (((i) < (unsigned int)TABCAP) ? table[i]                       \
                                             : run_adj_fallback(cumx, radj, (i), nblk))

// ---- pass A: degree -> dinv, xd (no gather in the chain) ----
__global__ __launch_bounds__(BLOCK_A) void deg_dinv_kernel(
    const unsigned long long* __restrict__ payload,
    const unsigned int* __restrict__ rowOffT,
    const float* __restrict__ x,
    float* __restrict__ dinv, float* __restrict__ xd,
    int N, int nb, int nblk) {
    __shared__ unsigned int cumx[MAXBLK];
    __shared__ int          radj[MAXBLK];
    __shared__ float        acc[CHUNK];
    __shared__ int          table[TABCAP];
    __shared__ unsigned int wsum[16];
    __shared__ unsigned int totsh;
    AGG_PROLOGUE
    unsigned int i = t;
    for (; i + 3u * BLOCK_A < total; i += 4u * BLOCK_A) {
        const unsigned int i0 = i, i1 = i + BLOCK_A, i2 = i + 2u * BLOCK_A,
                           i3 = i + 3u * BLOCK_A;
        const int a0 = TAB(i0), a1 = TAB(i1), a2 = TAB(i2), a3 = TAB(i3);
        const unsigned long long p0 = payload[(unsigned int)(a0 + (int)i0)];
        const unsigned long long p1 = payload[(unsigned int)(a1 + (int)i1)];
        const unsigned long long p2 = payload[(unsigned int)(a2 + (int)i2)];
        const unsigned long long p3 = payload[(unsigned int)(a3 + (int)i3)];
        atomicAdd(&acc[(unsigned int)p0 & (CHUNK - 1)],
                  __uint_as_float((unsigned int)(p0 >> 32)));
        atomicAdd(&acc[(unsigned int)p1 & (CHUNK - 1)],
                  __uint_as_float((unsigned int)(p1 >> 32)));
        atomicAdd(&acc[(unsigned int)p2 & (CHUNK - 1)],
                  __uint_as_float((unsigned int)(p2 >> 32)));
        atomicAdd(&acc[(unsigned int)p3 & (CHUNK - 1)],
                  __uint_as_float((unsigned int)(p3 >> 32)));
    }
    for (; i < total; i += BLOCK_A) {
        const int adj = TAB(i);
        const unsigned long long p = payload[(unsigned int)(adj + (int)i)];
        atomicAdd(&acc[(unsigned int)p & (CHUNK - 1)],
                  __uint_as_float((unsigned int)(p >> 32)));
    }
    __syncthreads();
    const int n = b * CHUNK + t;
    if (t < CHUNK && n < N) {
        const float d = acc[t] + 1.0f;           // self-loop fill 1.0
        const float r = (d > 0.0f) ? rsqrtf(d) : 0.0f;
        dinv[n] = r;
        xd[n]   = r * x[n];
    }
}

// ---- pass B: s -> relu-MLP -> gd ----
__global__ __launch_bounds__(BLOCK_A) void s_gamma_kernel(
    const unsigned long long* __restrict__ payload,
    const unsigned int* __restrict__ rowOffT,
    const float* __restrict__ dinv,
    const float* __restrict__ xd,
    const float* __restrict__ W1,    // [16]
    const float* __restrict__ b1,    // [16]
    const float* __restrict__ W2,    // [16][2]
    float* __restrict__ gd, int N, int nb, int nblk) {
    __shared__ unsigned int cumx[MAXBLK];
    __shared__ int          radj[MAXBLK];
    __shared__ float        acc[CHUNK];
    __shared__ int          table[TABCAP];
    __shared__ unsigned int wsum[16];
    __shared__ unsigned int totsh;
    AGG_PROLOGUE
    unsigned int i = t;
    for (; i + 3u * BLOCK_A < total; i += 4u * BLOCK_A) {
        const unsigned int i0 = i, i1 = i + BLOCK_A, i2 = i + 2u * BLOCK_A,
                           i3 = i + 3u * BLOCK_A;
        const int a0 = TAB(i0), a1 = TAB(i1), a2 = TAB(i2), a3 = TAB(i3);
        const unsigned long long p0 = payload[(unsigned int)(a0 + (int)i0)];
        const unsigned long long p1 = payload[(unsigned int)(a1 + (int)i1)];
        const unsigned long long p2 = payload[(unsigned int)(a2 + (int)i2)];
        const unsigned long long p3 = payload[(unsigned int)(a3 + (int)i3)];
        const float f0 = xd[(int)(((unsigned int)p0) >> LOG_CHUNK)];
        const float f1 = xd[(int)(((unsigned int)p1) >> LOG_CHUNK)];
        const float f2 = xd[(int)(((unsigned int)p2) >> LOG_CHUNK)];
        const float f3 = xd[(int)(((unsigned int)p3) >> LOG_CHUNK)];
        atomicAdd(&acc[(unsigned int)p0 & (CHUNK - 1)],
                  __uint_as_float((unsigned int)(p0 >> 32)) * f0);
        atomicAdd(&acc[(unsigned int)p1 & (CHUNK - 1)],
                  __uint_as_float((unsigned int)(p1 >> 32)) * f1);
        atomicAdd(&acc[(unsigned int)p2 & (CHUNK - 1)],
                  __uint_as_float((unsigned int)(p2 >> 32)) * f2);
        atomicAdd(&acc[(unsigned int)p3 & (CHUNK - 1)],
                  __uint_as_float((unsigned int)(p3 >> 32)) * f3);
    }
    for (; i < total; i += BLOCK_A) {
        const int adj = TAB(i);
        const unsigned long long p = payload[(unsigned int)(adj + (int)i)];
        atomicAdd(&acc[(unsigned int)p & (CHUNK - 1)],
                  __uint_as_float((unsigned int)(p >> 32)) *
                      xd[(int)(((unsigned int)p) >> LOG_CHUNK)]);
    }
    __syncthreads();
    const int n = b * CHUNK + t;
    if (t < CHUNK && n < N) {
        const float dv = dinv[n];
        const float sv = dv * (acc[t] + xd[n]);   // + self-loop dv*dv*x[n]
        float g = 0.0f;
#pragma unroll
        for (int f = 0; f < 16; ++f) {
            const float h = fmaxf(sv * W1[f] + b1[f], 0.0f);   // relu(layer1)
            g += h * (W2[2 * f + 1] - W2[2 * f + 0]);          // gamma = g1-g0
        }
        gd[n] = dv * g;                           // pre-scaled for layer 2
    }
}

// ---- pass C: d -> log_softmax out ----
__global__ __launch_bounds__(BLOCK_A) void d_out_kernel(
    const unsigned long long* __restrict__ payload,
    const unsigned int* __restrict__ rowOffT,
    const float* __restrict__ dinv,
    const float* __restrict__ gd,
    const float* __restrict__ b2,    // [2]
    float* __restrict__ out, int N, int nb, int nblk) {
    __shared__ unsigned int cumx[MAXBLK];
    __shared__ int          radj[MAXBLK];
    __shared__ float        acc[CHUNK];
    __shared__ int          table[TABCAP];
    __shared__ unsigned int wsum[16];
    __shared__ unsigned int totsh;
    AGG_PROLOGUE
    unsigned int i = t;
    for (; i + 3u * BLOCK_A < total; i += 4u * BLOCK_A) {
        const unsigned int i0 = i, i1 = i + BLOCK_A, i2 = i + 2u * BLOCK_A,
                           i3 = i + 3u * BLOCK_A;
        const int a0 = TAB(i0), a1 = TAB(i1), a2 = TAB(i2), a3 = TAB(i3);
        const unsigned long long p0 = payload[(unsigned int)(a0 + (int)i0)];
        const unsigned long long p1 = payload[(unsigned int)(a1 + (int)i1)];
        const unsigned long long p2 = payload[(unsigned int)(a2 + (int)i2)];
        const unsigned long long p3 = payload[(unsigned int)(a3 + (int)i3)];
        const float f0 = gd[(int)(((unsigned int)p0) >> LOG_CHUNK)];
        const float f1 = gd[(int)(((unsigned int)p1) >> LOG_CHUNK)];
        const float f2 = gd[(int)(((unsigned int)p2) >> LOG_CHUNK)];
        const float f3 = gd[(int)(((unsigned int)p3) >> LOG_CHUNK)];
        atomicAdd(&acc[(unsigned int)p0 & (CHUNK - 1)],
                  __uint_as_float((unsigned int)(p0 >> 32)) * f0);
        atomicAdd(&acc[(unsigned int)p1 & (CHUNK - 1)],
                  __uint_as_float((unsigned int)(p1 >> 32)) * f1);
        atomicAdd(&acc[(unsigned int)p2 & (CHUNK - 1)],
                  __uint_as_float((unsigned int)(p2 >> 32)) * f2);
        atomicAdd(&acc[(unsigned int)p3 & (CHUNK - 1)],
                  __uint_as_float((unsigned int)(p3 >> 32)) * f3);
    }
    for (; i < total; i += BLOCK_A) {
        const int adj = TAB(i);
        const unsigned long long p = payload[(unsigned int)(adj + (int)i)];
        atomicAdd(&acc[(unsigned int)p & (CHUNK - 1)],
                  __uint_as_float((unsigned int)(p >> 32)) *
                      gd[(int)(((unsigned int)p) >> LOG_CHUNK)]);
    }
    __syncthreads();
    const int n = b * CHUNK + t;
    if (t < CHUNK && n < N) {
        const float dv = dinv[n];
        const float d = dv * (acc[t] + gd[n]) + (b2[1] - b2[0]);
        // 2-class log_softmax from d = a1 - a0 (stable)
        const float lse = fmaxf(d, 0.0f) + log1pf(expf(-fabsf(d)));
        out[2 * n + 0] = -lse;
        out[2 * n + 1] = d - lse;
    }
}

// ======================= fallback: R3 global-atomic path =======================

static constexpr int BLOCK = 256;

__global__ void zero_kernel(float* __restrict__ a, float* __restrict__ b, int n2) {
    int i = blockIdx.x * blockDim.x + threadIdx.x;
    if (i < n2) { a[i] = 0.0f; b[i] = 0.0f; }
}
__global__ void deg_kernel(const int* __restrict__ dst, const float* __restrict__ w,
                           float* __restrict__ deg, int E) {
    int e = blockIdx.x * blockDim.x + threadIdx.x;
    if (e < E) atomicAdd(&deg[dst[e]], w[e]);
}
__global__ void dinv_kernel(float* __restrict__ deg, int N) {
    int n = blockIdx.x * blockDim.x + threadIdx.x;
    if (n < N) {
        float d = deg[n] + 1.0f;
        deg[n] = (d > 0.0f) ? rsqrtf(d) : 0.0f;
    }
}
__global__ void s_kernel(const int* __restrict__ src, const int* __restrict__ dst,
                         const float* __restrict__ w, const float* __restrict__ dinv,
                         const float* __restrict__ x, float* __restrict__ s, int E) {
    int e = blockIdx.x * blockDim.x + threadIdx.x;
    if (e < E) {
        int si = src[e], di = dst[e];
        atomicAdd(&s[di], dinv[si] * w[e] * dinv[di] * x[si]);
    }
}
__global__ void g_kernel(const float* __restrict__ s, const float* __restrict__ dinv,
                         const float* __restrict__ x, const float* __restrict__ W1,
                         const float* __restrict__ b1, const float* __restrict__ W2,
                         float2* __restrict__ g, int N) {
    int n = blockIdx.x * blockDim.x + threadIdx.x;
    if (n < N) {
        float dv = dinv[n];
        float sv = s[n] + dv * dv * x[n];
        float g0 = 0.0f, g1 = 0.0f;
#pragma unroll
        for (int f = 0; f < 16; ++f) {
            float h = fmaxf(sv * W1[f] + b1[f], 0.0f);
            g0 += h * W2[2 * f + 0];
            g1 += h * W2[2 * f + 1];
        }
        g[n] = make_float2(g0, g1);
    }
}
__global__ void agg2_kernel(const int* __restrict__ src, const int* __restrict__ dst,
                            const float* __restrict__ w, const float* __restrict__ dinv,
                            const float2* __restrict__ g, float* __restrict__ agg, int E) {
    int e = blockIdx.x * blockDim.x + threadIdx.x;
    if (e < E) {
        int si = src[e], di = dst[e];
        float norm = dinv[si] * w[e] * dinv[di];
        float2 gv = g[si];
        atomicAdd(&agg[2 * di + 0], norm * gv.x);
        atomicAdd(&agg[2 * di + 1], norm * gv.y);
    }
}
__global__ void out_kernel(float* __restrict__ out, const float* __restrict__ dinv,
                           const float2* __restrict__ g, const float* __restrict__ b2, int N) {
    int n = blockIdx.x * blockDim.x + threadIdx.x;
    if (n < N) {
        float dv2 = dinv[n] * dinv[n];
        float2 gv = g[n];
        float a0 = out[2 * n + 0] + dv2 * gv.x + b2[0];
        float a1 = out[2 * n + 1] + dv2 * gv.y + b2[1];
        float m = fmaxf(a0, a1);
        float lse = m + logf(expf(a0 - m) + expf(a1 - m));
        out[2 * n + 0] = a0 - lse;
        out[2 * n + 1] = a1 - lse;
    }
}

// ======================= launch =======================

extern "C" void kernel_launch(void* const* d_in, const int* in_sizes, int n_in,
                              void* d_out, int out_size, void* d_ws, size_t ws_size,
                              hipStream_t stream) {
    const float* x  = (const float*)d_in[0];
    const int*   ei = (const int*)d_in[1];     // [2, E] delivered as int32
    const float* w  = (const float*)d_in[2];
    const float* W1 = (const float*)d_in[3];
    const float* b1 = (const float*)d_in[4];
    const float* W2 = (const float*)d_in[5];
    const float* b2 = (const float*)d_in[6];
    float* out = (float*)d_out;

    const int N = in_sizes[0];
    const int E = in_sizes[2];
    const int* src = ei;
    const int* dst = ei + E;

    const int nb   = (N + CHUNK - 1) / CHUNK;   // 391
    const int nblk = (E + EPB - 1) / EPB;       // 782

    // ws layout: payload | rowOffT | dinv | xd | gd
    size_t off = 0;
    size_t payload_off = off;  off += (size_t)nblk * EPB * 8;
    size_t rowoff_off  = off;  off += (size_t)(nb + 1) * nblk * 4;
    off = (off + 7) & ~(size_t)7;
    size_t dinv_off    = off;  off += (size_t)N * 4;
    size_t xd_off      = off;  off += (size_t)N * 4;
    size_t gd_off      = off;  off += (size_t)N * 4;
    const size_t required = off;

    const bool fits = (nb <= MAXNB && nb <= BLOCK_S && nblk <= MAXBLK &&
                       nblk <= BLOCK_A && (E % 4) == 0 && ws_size >= required);

    if (fits) {
        char* wsb = (char*)d_ws;
        unsigned long long* payload = (unsigned long long*)(wsb + payload_off);
        unsigned int* rowOffT = (unsigned int*)(wsb + rowoff_off);
        float* dinv = (float*)(wsb + dinv_off);
        float* xd   = (float*)(wsb + xd_off);
        float* gd   = (float*)(wsb + gd_off);

        scatter_kernel <<<nblk, BLOCK_S, 0, stream>>>(src, dst, w, rowOffT, payload,
                                                      E, nb, nblk);
        deg_dinv_kernel<<<nb, BLOCK_A, 0, stream>>>(payload, rowOffT, x,
                                                    dinv, xd, N, nb, nblk);
        s_gamma_kernel <<<nb, BLOCK_A, 0, stream>>>(payload, rowOffT, dinv, xd,
                                                    W1, b1, W2, gd, N, nb, nblk);
        d_out_kernel   <<<nb, BLOCK_A, 0, stream>>>(payload, rowOffT, dinv, gd, b2,
                                                    out, N, nb, nblk);
    } else {
        // R3 fallback: global-atomic path (needs 4N floats of ws)
        float*  ws   = (float*)d_ws;
        float*  dinv = ws;
        float*  s    = ws + (size_t)N;
        float2* g    = (float2*)(ws + (size_t)2 * N);
        const int gridE  = (E + BLOCK - 1) / BLOCK;
        const int gridN  = (N + BLOCK - 1) / BLOCK;
        const int gridN2 = (2 * N + BLOCK - 1) / BLOCK;
        zero_kernel<<<gridN2, BLOCK, 0, stream>>>(ws, out, 2 * N);
        deg_kernel <<<gridE,  BLOCK, 0, stream>>>(dst, w, dinv, E);
        dinv_kernel<<<gridN,  BLOCK, 0, stream>>>(dinv, N);
        s_kernel   <<<gridE,  BLOCK, 0, stream>>>(src, dst, w, dinv, x, s, E);
        g_kernel   <<<gridN,  BLOCK, 0, stream>>>(s, dinv, x, W1, b1, W2, g, N);
        agg2_kernel<<<gridE,  BLOCK, 0, stream>>>(src, dst, w, dinv, g, out, E);
        out_kernel <<<gridN,  BLOCK, 0, stream>>>(out, dinv, g, b2, N);
    }
}